// Round 12
// baseline (46586.569 us; speedup 1.0000x reference)
//
#include <hip/hip_runtime.h>
#include <math.h>

// ---------------------------------------------------------------------------
// GameProcessor round 12: r7 phase structure (3 rounds/level, two-hop
// sense-epoch barrier + acquire fence, fp32 LDS weights) with:
//  * 512 blocks = 256 dim-pairs x 2 game-halves. Blocks b and b+256 hold the
//    SAME dim-pair weights but process disjoint game halves (w%2) -> total
//    LLC traffic unchanged vs r7 (r8's mistake was 1 dim/block = 2x traffic),
//    waves/CU doubles to 32. __launch_bounds__(1024,8) caps VGPR<=64 so
//    2 blocks/CU co-residency is guaranteed (512 = 256 CU x 2; r8-proven).
//  * Per-level metadata staged in LDS once (levelList/teams/a_won) - removes
//    2 serial post-fence LLC misses per task in phases A and C.
//  * Phase bodies byte-identical to r11; stash indexed w>>1 (own half only).
//  * Phase D: whole-block per game, block w (w < W < 512).
// ---------------------------------------------------------------------------

#define NG   30000
#define NT   364
#define ND   512
#define NF   28
#define NH   128
#define NCIN 1053
#define NB   512
#define BLK  1024
#define WCAP 192   // > max level width (<=182)

__device__ __forceinline__ float sigmf(float x) { return 1.0f / (1.0f + expf(-x)); }

__device__ __forceinline__ void astore_f(float* p, float v) {
  __hip_atomic_store(p, v, __ATOMIC_RELAXED, __HIP_MEMORY_SCOPE_AGENT);
}
__device__ __forceinline__ void astore_f2(float* p, float x, float y) {
  float2 v = make_float2(x, y);
  unsigned long long u; __builtin_memcpy(&u, &v, 8);
  __hip_atomic_store((unsigned long long*)p, u, __ATOMIC_RELAXED, __HIP_MEMORY_SCOPE_AGENT);
}

__global__ void zero_kernel(int* p, int n) {
  int i = blockIdx.x * blockDim.x + threadIdx.x;
  if (i < n) p[i] = 0;
}

__global__ void deps_kernel(const int* __restrict__ ta, const int* __restrict__ tb,
                            int* __restrict__ dep0, int* __restrict__ dep1) {
  int g = blockIdx.x * blockDim.x + threadIdx.x;
  if (g >= NG) return;
  int a = ta[g], b = tb[g];
  int d0 = -1, d1 = -1;
  for (int p = g - 1; p >= 0; --p) {
    int pa = ta[p], pb = tb[p];
    if (d0 < 0 && (pa == a || pb == a)) d0 = p;
    if (d1 < 0 && (pa == b || pb == b)) d1 = p;
    if (d0 >= 0 && d1 >= 0) break;
  }
  dep0[g] = d0;
  dep1[g] = d1;
}

__global__ void levels_kernel(const int* __restrict__ d0a, const int* __restrict__ d1a,
                              int* __restrict__ level, int* __restrict__ nLevels) {
  __shared__ int lv[1024];
  __shared__ int changed;
  __shared__ int smax;
  const int tid = threadIdx.x;
  int localMax = 0;
  if (tid == 0) smax = 0;
  for (int base = 0; base < NG; base += 1024) {
    const int g = base + tid;
    const bool val = g < NG;
    int ic0 = -1, ic1 = -1, b = 0;
    if (val) {
      int d0 = d0a[g], d1 = d1a[g];
      if (d0 >= 0) { if (d0 < base) b = max(b, level[d0] + 1); else ic0 = d0 - base; }
      if (d1 >= 0) { if (d1 < base) b = max(b, level[d1] + 1); else ic1 = d1 - base; }
    }
    lv[tid] = b;
    __syncthreads();
    for (;;) {
      if (tid == 0) changed = 0;
      __syncthreads();
      int nl = lv[tid];
      if (ic0 >= 0) nl = max(nl, lv[ic0] + 1);
      if (ic1 >= 0) nl = max(nl, lv[ic1] + 1);
      if (val && nl != lv[tid]) { lv[tid] = nl; changed = 1; }
      __syncthreads();
      if (!changed) break;
    }
    if (val) { level[g] = lv[tid]; localMax = max(localMax, lv[tid]); }
    __syncthreads();
  }
  atomicMax(&smax, localMax);
  __syncthreads();
  if (tid == 0) nLevels[0] = smax + 1;
}

__global__ void sort_kernel(const int* __restrict__ level, const int* __restrict__ nLevels,
                            int* __restrict__ hist, int* __restrict__ cursor,
                            int* __restrict__ levelStart, int* __restrict__ levelList) {
  const int tid = threadIdx.x;
  const int nL = nLevels[0];
  for (int i = tid; i < NG; i += 1024) { hist[i] = 0; cursor[i] = 0; }
  __syncthreads();
  for (int g = tid; g < NG; g += 1024) atomicAdd(&hist[level[g]], 1);
  __syncthreads();
  if (tid == 0) {
    int acc = 0;
    for (int i = 0; i < nL; ++i) { levelStart[i] = acc; acc += hist[i]; }
    levelStart[nL] = acc;
  }
  __syncthreads();
  for (int g = tid; g < NG; g += 1024) {
    int l = level[g];
    int off = atomicAdd(&cursor[l], 1);
    levelList[levelStart[l] + off] = g;
  }
}

// Distributed sense-epoch grid barrier with acquire fence (r3/r7-proven).
__device__ __forceinline__ void grid_bar(int* go, int* arr, int& epoch) {
  ++epoch;
  __syncthreads();
  if (blockIdx.x == 0) {
    const int t = threadIdx.x;
    if (t >= 1 && t < NB) {
      while (__hip_atomic_load(arr + t * 32, __ATOMIC_RELAXED, __HIP_MEMORY_SCOPE_AGENT) < epoch)
        __builtin_amdgcn_s_sleep(1);
    }
    __builtin_amdgcn_fence(__ATOMIC_ACQUIRE, "agent");
    __syncthreads();
    if (t == 0)
      __hip_atomic_store(go, epoch, __ATOMIC_RELEASE, __HIP_MEMORY_SCOPE_AGENT);
  } else {
    if (threadIdx.x == 0) {
      __hip_atomic_store(arr + blockIdx.x * 32, epoch, __ATOMIC_RELEASE, __HIP_MEMORY_SCOPE_AGENT);
      while (__hip_atomic_load(go, __ATOMIC_RELAXED, __HIP_MEMORY_SCOPE_AGENT) < epoch)
        __builtin_amdgcn_s_sleep(1);
      __builtin_amdgcn_fence(__ATOMIC_ACQUIRE, "agent");
    }
    __syncthreads();
  }
}

__global__ __launch_bounds__(BLK, 8)
void game_kernel(const float* __restrict__ Wp,   const float* __restrict__ bp,
                 const float* __restrict__ W_ih, const float* __restrict__ b_ih,
                 const float* __restrict__ W_hh, const float* __restrict__ b_hh,
                 const float* __restrict__ ln_g, const float* __restrict__ ln_b,
                 const float* __restrict__ Wi1,  const float* __restrict__ bi1,
                 const float* __restrict__ Wi2,  const float* __restrict__ bi2,
                 const float* __restrict__ fA,   const float* __restrict__ fB,
                 const int* __restrict__ team_a, const int* __restrict__ team_b,
                 const int* __restrict__ a_won,
                 float* __restrict__ emb, float* __restrict__ ctx,
                 const int* __restrict__ levelStart, const int* __restrict__ levelList,
                 const int* __restrict__ nLevels,
                 float* __restrict__ nhbuf, float* __restrict__ hidbuf,
                 int* __restrict__ go, int* __restrict__ arr, int Wcap) {
  const int b    = blockIdx.x;
  const int tid  = threadIdx.x;
  const int lane = tid & 63;
  const int wave = tid >> 6;
  const int grpq = lane >> 4;     // 16-lane group id within wave (0..3)
  const int l4   = lane & 15;
  const int pairid = b & 255;     // dim-pair id (shared by b and b+256)
  const int ghalf  = b >> 8;      // game-half (w % 2 == ghalf)
  const int d0   = 2 * pairid;    // owned output dims {d0, d0+1}
  const int r_b  = pairid >> 7;   // owned hidden unit (row, index)
  const int h_b  = pairid & 127;

  // ---- LDS: fp32 weights, float4-packed {d0/e0, d1/e0, d0/e1, d1/e1} ----
  __shared__ float4 wpS4[256];        // Wp cols 0..511   (e_self)
  __shared__ float4 wpO4[256];        // Wp cols 512..1023 (e_opp)
  __shared__ float2 wpT2[32];         // Wp cols 1024..1052
  __shared__ float4 wih4[768];        // W_ih [gate*256 + pair]
  __shared__ float4 whh4[768];        // W_hh
  __shared__ float2 wi12[256];        // Wi1[h_b] pairs
  __shared__ float4 sStash[WCAP / 2][4];  // own half: {r0,z0},{n0,es0},{r1,z1},{n1,es1}
  __shared__ int   sG[WCAP], sTa[WCAP], sTb[WCAP];
  __shared__ float sAw[WCAP];
  __shared__ float sImp[2];
  __shared__ float sRed[2][16];
  __shared__ float sStat[4];

  if (tid < 256) {
    const int p = tid;
    wpS4[p] = make_float4(Wp[(size_t)d0 * NCIN + 2 * p],
                          Wp[(size_t)(d0 + 1) * NCIN + 2 * p],
                          Wp[(size_t)d0 * NCIN + 2 * p + 1],
                          Wp[(size_t)(d0 + 1) * NCIN + 2 * p + 1]);
    wpO4[p] = make_float4(Wp[(size_t)d0 * NCIN + ND + 2 * p],
                          Wp[(size_t)(d0 + 1) * NCIN + ND + 2 * p],
                          Wp[(size_t)d0 * NCIN + ND + 2 * p + 1],
                          Wp[(size_t)(d0 + 1) * NCIN + ND + 2 * p + 1]);
    wi12[p] = make_float2(Wi1[(size_t)h_b * ND + 2 * p],
                          Wi1[(size_t)h_b * ND + 2 * p + 1]);
  } else if (tid < 288) {
    const int t = tid - 256;
    wpT2[t] = (t < NF + 1)
        ? make_float2(Wp[(size_t)d0 * NCIN + 2 * ND + t],
                      Wp[(size_t)(d0 + 1) * NCIN + 2 * ND + t])
        : make_float2(0.f, 0.f);
  }
  if (tid < 768) {
    const int gt = tid >> 8, p = tid & 255;
    wih4[tid] = make_float4(W_ih[((size_t)gt * ND + d0) * ND + 2 * p],
                            W_ih[((size_t)gt * ND + d0 + 1) * ND + 2 * p],
                            W_ih[((size_t)gt * ND + d0) * ND + 2 * p + 1],
                            W_ih[((size_t)gt * ND + d0 + 1) * ND + 2 * p + 1]);
    whh4[tid] = make_float4(W_hh[((size_t)gt * ND + d0) * ND + 2 * p],
                            W_hh[((size_t)gt * ND + d0 + 1) * ND + 2 * p],
                            W_hh[((size_t)gt * ND + d0) * ND + 2 * p + 1],
                            W_hh[((size_t)gt * ND + d0 + 1) * ND + 2 * p + 1]);
  }

  const float bp0 = bp[d0], bp1 = bp[d0 + 1];
  float bih[6], bhh[6];   // [gate*2 + dim]
#pragma unroll
  for (int gt = 0; gt < 3; ++gt)
#pragma unroll
    for (int d = 0; d < 2; ++d) {
      bih[gt * 2 + d] = b_ih[gt * ND + d0 + d];
      bhh[gt * 2 + d] = b_hh[gt * ND + d0 + d];
    }
  const float bi1h = bi1[h_b];
  const float bi2v = bi2[0];
  const float2 w2p = ((const float2*)Wi2)[lane];
  float2 lg2 = make_float2(0.f, 0.f), lb2 = lg2;
  if (tid < 512) {
    lg2 = ((const float2*)ln_g)[tid & 255];
    lb2 = ((const float2*)ln_b)[tid & 255];
  }
  __syncthreads();

  const int nL = nLevels[0];
  int epoch = 0;

  for (int L = 0; L < nL; ++L) {
    const int s = levelStart[L], e_ = levelStart[L + 1];
    for (int cs = s; cs < e_; cs += Wcap) {
      const int W = min(e_ - cs, Wcap);

      // ---- stage per-level metadata in LDS (immutable -> cache-valid) ----
      if (tid < W) {
        const int g = levelList[cs + tid];
        sG[tid] = g;
        sTa[tid] = team_a[g];
        sTb[tid] = team_b[g];
        sAw[tid] = (float)a_won[g];
      }
      __syncthreads();

      // ===== R1: phase A (own half: proj both rows -> ctx; gh+es stash) ====
      for (int w = (wave * 4 + grpq) * 2 + ghalf; w < W; w += 128) {
        const int g = sG[w];
        const int ta = sTa[w], tb = sTb[w];
        const float aw = sAw[w];
        const int sw = w >> 1;
        const float* rowA = emb + (size_t)ta * ND;
        const float* rowB = emb + (size_t)tb * ND;
        const float2 es0 = *(const float2*)(rowA + d0);
        const float2 es1 = *(const float2*)(rowB + d0);
        float acc[16];
#pragma unroll
        for (int i = 0; i < 16; ++i) acc[i] = 0.f;
#pragma unroll 8
        for (int j = 0; j < 16; ++j) {
          const int p = j * 16 + l4;
          const float2 va = *(const float2*)(rowA + 2 * p);
          const float2 vb = *(const float2*)(rowB + 2 * p);
          const float4 wS = wpS4[p];
          const float4 wO = wpO4[p];
          acc[0] += va.x * wS.x + va.y * wS.z + vb.x * wO.x + vb.y * wO.z;
          acc[1] += va.x * wS.y + va.y * wS.w + vb.x * wO.y + vb.y * wO.w;
          acc[2] += vb.x * wS.x + vb.y * wS.z + va.x * wO.x + va.y * wO.z;
          acc[3] += vb.x * wS.y + vb.y * wS.w + va.x * wO.y + va.y * wO.w;
#pragma unroll
          for (int gt = 0; gt < 3; ++gt) {
            const float4 q = whh4[gt * 256 + p];
            acc[4 + gt * 2 + 0]  += va.x * q.x + va.y * q.z;
            acc[4 + gt * 2 + 1]  += va.x * q.y + va.y * q.w;
            acc[10 + gt * 2 + 0] += vb.x * q.x + vb.y * q.z;
            acc[10 + gt * 2 + 1] += vb.x * q.y + vb.y * q.w;
          }
        }
#pragma unroll
        for (int j = 0; j < 2; ++j) {
          const int t = j * 16 + l4;
          if (t < NF + 1) {
            const float cv0 = (t < NF) ? fA[(size_t)g * NF + t] : aw;
            const float cv1 = (t < NF) ? fB[(size_t)g * NF + t] : 1.0f - aw;
            const float2 wt = wpT2[t];
            acc[0] += cv0 * wt.x; acc[1] += cv0 * wt.y;
            acc[2] += cv1 * wt.x; acc[3] += cv1 * wt.y;
          }
        }
#pragma unroll
        for (int off = 8; off > 0; off >>= 1) {
#pragma unroll
          for (int i = 0; i < 16; ++i) acc[i] += __shfl_xor(acc[i], off);
        }
        if (l4 == 0) {
          astore_f2(ctx + (size_t)g * 1024 + d0,
                    fmaxf(acc[0] + bp0, 0.f), fmaxf(acc[1] + bp1, 0.f));
          astore_f2(ctx + (size_t)g * 1024 + ND + d0,
                    fmaxf(acc[2] + bp0, 0.f), fmaxf(acc[3] + bp1, 0.f));
          sStash[sw][0] = make_float4(acc[4], acc[5], acc[6], acc[7]);
          sStash[sw][1] = make_float4(acc[8], acc[9], es0.x, es0.y);
          sStash[sw][2] = make_float4(acc[10], acc[11], acc[12], acc[13]);
          sStash[sw][3] = make_float4(acc[14], acc[15], es1.x, es1.y);
        }
      }
      grid_bar(go, arr, epoch);

      // ===== R2: phase C (own half: gates -> nh, both rows) + B1 =====
      for (int w = (wave * 4 + grpq) * 2 + ghalf; w < W; w += 128) {
        const int g = sG[w];
        const int sw = w >> 1;
        const float* p0 = ctx + (size_t)g * 1024;
        const float* p1 = p0 + ND;
        float acc[13];
#pragma unroll
        for (int i = 0; i < 13; ++i) acc[i] = 0.f;
#pragma unroll 8
        for (int j = 0; j < 16; ++j) {
          const int p = j * 16 + l4;
          const float2 x0 = *(const float2*)(p0 + 2 * p);
          const float2 x1 = *(const float2*)(p1 + 2 * p);
#pragma unroll
          for (int gt = 0; gt < 3; ++gt) {
            const float4 q = wih4[gt * 256 + p];
            acc[gt * 2 + 0]     += x0.x * q.x + x0.y * q.z;
            acc[gt * 2 + 1]     += x0.x * q.y + x0.y * q.w;
            acc[6 + gt * 2 + 0] += x1.x * q.x + x1.y * q.z;
            acc[6 + gt * 2 + 1] += x1.x * q.y + x1.y * q.w;
          }
          const float2 wi = wi12[p];
          const float2 xr = r_b ? x1 : x0;
          acc[12] += xr.x * wi.x + xr.y * wi.y;
        }
#pragma unroll
        for (int off = 8; off > 0; off >>= 1) {
#pragma unroll
          for (int i = 0; i < 13; ++i) acc[i] += __shfl_xor(acc[i], off);
        }
        if (l4 == 0) {
          const float4 s0 = sStash[sw][0], s1 = sStash[sw][1];
          const float4 s2 = sStash[sw][2], s3 = sStash[sw][3];
          {
            const float r0 = sigmf(acc[0] + bih[0] + s0.x + bhh[0]);
            const float r1 = sigmf(acc[1] + bih[1] + s0.y + bhh[1]);
            const float z0 = sigmf(acc[2] + bih[2] + s0.z + bhh[2]);
            const float z1 = sigmf(acc[3] + bih[3] + s0.w + bhh[3]);
            const float n0 = tanhf(acc[4] + bih[4] + r0 * (s1.x + bhh[4]));
            const float n1 = tanhf(acc[5] + bih[5] + r1 * (s1.y + bhh[5]));
            astore_f2(nhbuf + (size_t)w * 1024 + d0,
                      (1.f - z0) * n0 + z0 * s1.z,
                      (1.f - z1) * n1 + z1 * s1.w);
          }
          {
            const float r0 = sigmf(acc[6] + bih[0] + s2.x + bhh[0]);
            const float r1 = sigmf(acc[7] + bih[1] + s2.y + bhh[1]);
            const float z0 = sigmf(acc[8] + bih[2] + s2.z + bhh[2]);
            const float z1 = sigmf(acc[9] + bih[3] + s2.w + bhh[3]);
            const float n0 = tanhf(acc[10] + bih[4] + r0 * (s3.x + bhh[4]));
            const float n1 = tanhf(acc[11] + bih[5] + r1 * (s3.y + bhh[5]));
            astore_f2(nhbuf + (size_t)w * 1024 + ND + d0,
                      (1.f - z0) * n0 + z0 * s3.z,
                      (1.f - z1) * n1 + z1 * s3.w);
          }
          astore_f(hidbuf + (size_t)w * 256 + r_b * NH + h_b,
                   fmaxf(acc[12] + bi1h, 0.f));
        }
      }
      grid_bar(go, arr, epoch);

      // ===== R3: phase D (whole block, game w = b): imp, blend, LN, write ==
      for (int w = b; w < W; w += NB) {
        const int ta = sTa[w], tb = sTb[w];
        if (wave < 2) {
          const float2 hv = *(const float2*)(hidbuf + (size_t)w * 256 + wave * NH + 2 * lane);
          float a = hv.x * w2p.x + hv.y * w2p.y;
#pragma unroll
          for (int off = 32; off > 0; off >>= 1) a += __shfl_xor(a, off);
          if (lane == 0) sImp[wave] = sigmf(a + bi2v);
        }
        __syncthreads();
        float ux = 0.f, uy = 0.f;
        if (tid < 512) {
          const int row = tid >> 8;
          const int e = 2 * (tid & 255);
          const int team = row ? tb : ta;
          const float imp = sImp[row];
          const float2 ev = *(const float2*)(emb + (size_t)team * ND + e);
          const float2 nv = *(const float2*)(nhbuf + (size_t)w * 1024 + (size_t)row * ND + e);
          ux = ev.x + imp * (nv.x - ev.x);
          uy = ev.y + imp * (nv.y - ev.y);
        }
        float sS = ux + uy, sQ = ux * ux + uy * uy;
#pragma unroll
        for (int off = 32; off > 0; off >>= 1) {
          sS += __shfl_xor(sS, off);
          sQ += __shfl_xor(sQ, off);
        }
        if (lane == 0) { sRed[0][wave] = sS; sRed[1][wave] = sQ; }
        __syncthreads();
        if (tid == 0) {
          const float S0 = sRed[0][0] + sRed[0][1] + sRed[0][2] + sRed[0][3];
          const float Q0 = sRed[1][0] + sRed[1][1] + sRed[1][2] + sRed[1][3];
          const float S1 = sRed[0][4] + sRed[0][5] + sRed[0][6] + sRed[0][7];
          const float Q1 = sRed[1][4] + sRed[1][5] + sRed[1][6] + sRed[1][7];
          const float mu0 = S0 * (1.0f / ND), mu1 = S1 * (1.0f / ND);
          const float v0 = Q0 * (1.0f / ND) - mu0 * mu0;
          const float v1 = Q1 * (1.0f / ND) - mu1 * mu1;
          sStat[0] = mu0; sStat[1] = 1.0f / sqrtf(v0 + 1e-5f);
          sStat[2] = mu1; sStat[3] = 1.0f / sqrtf(v1 + 1e-5f);
        }
        __syncthreads();
        if (tid < 512) {
          const int row = tid >> 8;
          const int e = 2 * (tid & 255);
          const float mu = sStat[row * 2], rs = sStat[row * 2 + 1];
          const float ox = (ux - mu) * rs * lg2.x + lb2.x;
          const float oy = (uy - mu) * rs * lg2.y + lb2.y;
          if (row == 0) {
            if (ta != tb) astore_f2(emb + (size_t)ta * ND + e, ox, oy);
          } else {
            astore_f2(emb + (size_t)tb * ND + e, ox, oy);
          }
        }
        __syncthreads();
      }
      grid_bar(go, arr, epoch);
    }
  }
}

extern "C" void kernel_launch(void* const* d_in, const int* in_sizes, int n_in,
                              void* d_out, int out_size, void* d_ws, size_t ws_size,
                              hipStream_t stream) {
  const float* emb_table = (const float*)d_in[0];
  const float* Wp    = (const float*)d_in[1];
  const float* bp    = (const float*)d_in[2];
  const float* W_ih  = (const float*)d_in[3];
  const float* b_ih  = (const float*)d_in[4];
  const float* W_hh  = (const float*)d_in[5];
  const float* b_hh  = (const float*)d_in[6];
  const float* ln_g  = (const float*)d_in[7];
  const float* ln_b  = (const float*)d_in[8];
  const float* Wi1   = (const float*)d_in[9];
  const float* bi1   = (const float*)d_in[10];
  const float* Wi2   = (const float*)d_in[11];
  const float* bi2   = (const float*)d_in[12];
  const float* fA    = (const float*)d_in[13];
  const float* fB    = (const float*)d_in[14];
  const int*   team_a = (const int*)d_in[15];
  const int*   team_b = (const int*)d_in[16];
  const int*   a_won  = (const int*)d_in[17];

  float* out = (float*)d_out;
  float* emb = out;
  float* ctx = out + (size_t)NT * ND;

  int* ip         = (int*)d_ws;
  int* go         = ip;                 // 1 line
  int* arr        = ip + 32;            // NB lines
  int* nLevels    = ip + 32 + NB * 32;
  int* dep0       = nLevels + 32;
  int* dep1       = dep0 + NG;
  int* level      = dep1 + NG;
  int* hist       = level + NG;
  int* cursor     = hist + NG;
  int* levelStart = cursor + NG;        // NG+2
  int* levelList  = levelStart + NG + 2;
  const int flagInts = 32 + NB * 32;
  size_t control = (size_t)((char*)(levelList + NG) - (char*)d_ws);
  control = (control + 255) & ~(size_t)255;

  int Wcap = WCAP;
  {
    size_t avail = (ws_size > control + 4096)
        ? (ws_size - control) / ((size_t)(1024 + 256) * sizeof(float))
        : 8;
    if (avail < (size_t)Wcap) Wcap = (int)avail;
    if (Wcap < 8) Wcap = 8;
  }
  float* nhbuf  = (float*)((char*)d_ws + control);
  float* hidbuf = nhbuf + (size_t)Wcap * 1024;

  hipMemcpyAsync(emb, emb_table, (size_t)NT * ND * sizeof(float),
                 hipMemcpyDeviceToDevice, stream);
  zero_kernel<<<(flagInts + 255) / 256, 256, 0, stream>>>(ip, flagInts);
  deps_kernel<<<(NG + 255) / 256, 256, 0, stream>>>(team_a, team_b, dep0, dep1);
  levels_kernel<<<1, 1024, 0, stream>>>(dep0, dep1, level, nLevels);
  sort_kernel<<<1, 1024, 0, stream>>>(level, nLevels, hist, cursor, levelStart, levelList);
  game_kernel<<<NB, BLK, 0, stream>>>(
      Wp, bp, W_ih, b_ih, W_hh, b_hh, ln_g, ln_b, Wi1, bi1, Wi2, bi2,
      fA, fB, team_a, team_b, a_won, emb, ctx,
      levelStart, levelList, nLevels, nhbuf, hidbuf, go, arr, Wcap);
}

// Round 13
// 23293.347 us; speedup vs baseline: 2.0000x; 2.0000x over previous
//
#include <hip/hip_runtime.h>
#include <math.h>

// ---------------------------------------------------------------------------
// GameProcessor round 13: r11 EXACT structure (3 rounds/level, fp32 LDS
// weights, 256 blocks x 1024 thr, 16-lane task groups, gh-fold, merged B1,
// unroll-8) with two isolated latency cuts:
//  * Barrier go-broadcast de-contention: 32 replicated go-lines; block b
//    polls goRep[b>>3] (<=8 readers/line vs 255 on one line). Block0 threads
//    0..31 release-store all replicas after acquire fence + syncthreads.
//  * Per-level metadata staged in LDS (levelList/teams/a_won) - removes 2
//    serial post-fence LLC hops per task (r12 idea, isolated from its fatal
//    512-block change).
// Memory-model law from r8/r9/r12 failures: 256 blocks / 1 per CU /
// fence-based coherence is the only stable config; 512 blocks + fences
// explodes FETCH to 15-16 GB.
// ---------------------------------------------------------------------------

#define NG   30000
#define NT   364
#define ND   512
#define NF   28
#define NH   128
#define NCIN 1053
#define NB   256
#define BLK  1024
#define WCAP 192   // > max level width

__device__ __forceinline__ float sigmf(float x) { return 1.0f / (1.0f + expf(-x)); }

__device__ __forceinline__ void astore_f(float* p, float v) {
  __hip_atomic_store(p, v, __ATOMIC_RELAXED, __HIP_MEMORY_SCOPE_AGENT);
}
__device__ __forceinline__ void astore_f2(float* p, float x, float y) {
  float2 v = make_float2(x, y);
  unsigned long long u; __builtin_memcpy(&u, &v, 8);
  __hip_atomic_store((unsigned long long*)p, u, __ATOMIC_RELAXED, __HIP_MEMORY_SCOPE_AGENT);
}

__global__ void zero_kernel(int* p, int n) {
  int i = blockIdx.x * blockDim.x + threadIdx.x;
  if (i < n) p[i] = 0;
}

__global__ void deps_kernel(const int* __restrict__ ta, const int* __restrict__ tb,
                            int* __restrict__ dep0, int* __restrict__ dep1) {
  int g = blockIdx.x * blockDim.x + threadIdx.x;
  if (g >= NG) return;
  int a = ta[g], b = tb[g];
  int d0 = -1, d1 = -1;
  for (int p = g - 1; p >= 0; --p) {
    int pa = ta[p], pb = tb[p];
    if (d0 < 0 && (pa == a || pb == a)) d0 = p;
    if (d1 < 0 && (pa == b || pb == b)) d1 = p;
    if (d0 >= 0 && d1 >= 0) break;
  }
  dep0[g] = d0;
  dep1[g] = d1;
}

__global__ void levels_kernel(const int* __restrict__ d0a, const int* __restrict__ d1a,
                              int* __restrict__ level, int* __restrict__ nLevels) {
  __shared__ int lv[1024];
  __shared__ int changed;
  __shared__ int smax;
  const int tid = threadIdx.x;
  int localMax = 0;
  if (tid == 0) smax = 0;
  for (int base = 0; base < NG; base += 1024) {
    const int g = base + tid;
    const bool val = g < NG;
    int ic0 = -1, ic1 = -1, b = 0;
    if (val) {
      int d0 = d0a[g], d1 = d1a[g];
      if (d0 >= 0) { if (d0 < base) b = max(b, level[d0] + 1); else ic0 = d0 - base; }
      if (d1 >= 0) { if (d1 < base) b = max(b, level[d1] + 1); else ic1 = d1 - base; }
    }
    lv[tid] = b;
    __syncthreads();
    for (;;) {
      if (tid == 0) changed = 0;
      __syncthreads();
      int nl = lv[tid];
      if (ic0 >= 0) nl = max(nl, lv[ic0] + 1);
      if (ic1 >= 0) nl = max(nl, lv[ic1] + 1);
      if (val && nl != lv[tid]) { lv[tid] = nl; changed = 1; }
      __syncthreads();
      if (!changed) break;
    }
    if (val) { level[g] = lv[tid]; localMax = max(localMax, lv[tid]); }
    __syncthreads();
  }
  atomicMax(&smax, localMax);
  __syncthreads();
  if (tid == 0) nLevels[0] = smax + 1;
}

__global__ void sort_kernel(const int* __restrict__ level, const int* __restrict__ nLevels,
                            int* __restrict__ hist, int* __restrict__ cursor,
                            int* __restrict__ levelStart, int* __restrict__ levelList) {
  const int tid = threadIdx.x;
  const int nL = nLevels[0];
  for (int i = tid; i < NG; i += 1024) { hist[i] = 0; cursor[i] = 0; }
  __syncthreads();
  for (int g = tid; g < NG; g += 1024) atomicAdd(&hist[level[g]], 1);
  __syncthreads();
  if (tid == 0) {
    int acc = 0;
    for (int i = 0; i < nL; ++i) { levelStart[i] = acc; acc += hist[i]; }
    levelStart[nL] = acc;
  }
  __syncthreads();
  for (int g = tid; g < NG; g += 1024) {
    int l = level[g];
    int off = atomicAdd(&cursor[l], 1);
    levelList[levelStart[l] + off] = g;
  }
}

// Two-hop sense-epoch barrier with acquire fence; go replicated on 32 lines.
__device__ __forceinline__ void grid_bar(int* goRep, int* arr, int& epoch) {
  ++epoch;
  __syncthreads();
  if (blockIdx.x == 0) {
    const int t = threadIdx.x;
    if (t >= 1 && t < NB) {
      while (__hip_atomic_load(arr + t * 32, __ATOMIC_RELAXED, __HIP_MEMORY_SCOPE_AGENT) < epoch)
        __builtin_amdgcn_s_sleep(1);
    }
    __builtin_amdgcn_fence(__ATOMIC_ACQUIRE, "agent");
    __syncthreads();
    if (t < 32)
      __hip_atomic_store(goRep + t * 32, epoch, __ATOMIC_RELEASE, __HIP_MEMORY_SCOPE_AGENT);
  } else {
    if (threadIdx.x == 0) {
      __hip_atomic_store(arr + blockIdx.x * 32, epoch, __ATOMIC_RELEASE, __HIP_MEMORY_SCOPE_AGENT);
      int* myGo = goRep + (blockIdx.x >> 3) * 32;
      while (__hip_atomic_load(myGo, __ATOMIC_RELAXED, __HIP_MEMORY_SCOPE_AGENT) < epoch)
        __builtin_amdgcn_s_sleep(1);
      __builtin_amdgcn_fence(__ATOMIC_ACQUIRE, "agent");
    }
    __syncthreads();
  }
}

__global__ __launch_bounds__(BLK, 4)
void game_kernel(const float* __restrict__ Wp,   const float* __restrict__ bp,
                 const float* __restrict__ W_ih, const float* __restrict__ b_ih,
                 const float* __restrict__ W_hh, const float* __restrict__ b_hh,
                 const float* __restrict__ ln_g, const float* __restrict__ ln_b,
                 const float* __restrict__ Wi1,  const float* __restrict__ bi1,
                 const float* __restrict__ Wi2,  const float* __restrict__ bi2,
                 const float* __restrict__ fA,   const float* __restrict__ fB,
                 const int* __restrict__ team_a, const int* __restrict__ team_b,
                 const int* __restrict__ a_won,
                 float* __restrict__ emb, float* __restrict__ ctx,
                 const int* __restrict__ levelStart, const int* __restrict__ levelList,
                 const int* __restrict__ nLevels,
                 float* __restrict__ nhbuf, float* __restrict__ hidbuf,
                 int* __restrict__ goRep, int* __restrict__ arr, int Wcap) {
  const int b    = blockIdx.x;
  const int tid  = threadIdx.x;
  const int lane = tid & 63;
  const int wave = tid >> 6;
  const int grpq = lane >> 4;     // 16-lane group id within wave (0..3)
  const int l4   = lane & 15;
  const int d0   = 2 * b;         // owned output dims {d0, d0+1}
  const int r_b  = b >> 7;        // owned hidden unit (row, index)
  const int h_b  = b & 127;

  // ---- LDS: fp32 weights, float4-packed {d0/e0, d1/e0, d0/e1, d1/e1} ----
  __shared__ float4 wpS4[256];        // Wp cols 0..511   (e_self)
  __shared__ float4 wpO4[256];        // Wp cols 512..1023 (e_opp)
  __shared__ float2 wpT2[32];         // Wp cols 1024..1052
  __shared__ float4 wih4[768];        // W_ih [gate*256 + pair]
  __shared__ float4 whh4[768];        // W_hh
  __shared__ float2 wi12[256];        // Wi1[h_b] pairs
  __shared__ float4 sStash[WCAP][4];  // per game: {r0,z0},{n0,es0},{r1,z1},{n1,es1}
  __shared__ int   sTa[WCAP], sTb[WCAP], sG[WCAP];
  __shared__ float sAw[WCAP];
  __shared__ float sImp[2];
  __shared__ float sRed[2][16];
  __shared__ float sStat[4];

  if (tid < 256) {
    const int p = tid;
    wpS4[p] = make_float4(Wp[(size_t)d0 * NCIN + 2 * p],
                          Wp[(size_t)(d0 + 1) * NCIN + 2 * p],
                          Wp[(size_t)d0 * NCIN + 2 * p + 1],
                          Wp[(size_t)(d0 + 1) * NCIN + 2 * p + 1]);
    wpO4[p] = make_float4(Wp[(size_t)d0 * NCIN + ND + 2 * p],
                          Wp[(size_t)(d0 + 1) * NCIN + ND + 2 * p],
                          Wp[(size_t)d0 * NCIN + ND + 2 * p + 1],
                          Wp[(size_t)(d0 + 1) * NCIN + ND + 2 * p + 1]);
    wi12[p] = make_float2(Wi1[(size_t)h_b * ND + 2 * p],
                          Wi1[(size_t)h_b * ND + 2 * p + 1]);
  } else if (tid < 288) {
    const int t = tid - 256;
    wpT2[t] = (t < NF + 1)
        ? make_float2(Wp[(size_t)d0 * NCIN + 2 * ND + t],
                      Wp[(size_t)(d0 + 1) * NCIN + 2 * ND + t])
        : make_float2(0.f, 0.f);
  }
  if (tid < 768) {
    const int gt = tid >> 8, p = tid & 255;
    wih4[tid] = make_float4(W_ih[((size_t)gt * ND + d0) * ND + 2 * p],
                            W_ih[((size_t)gt * ND + d0 + 1) * ND + 2 * p],
                            W_ih[((size_t)gt * ND + d0) * ND + 2 * p + 1],
                            W_ih[((size_t)gt * ND + d0 + 1) * ND + 2 * p + 1]);
    whh4[tid] = make_float4(W_hh[((size_t)gt * ND + d0) * ND + 2 * p],
                            W_hh[((size_t)gt * ND + d0 + 1) * ND + 2 * p],
                            W_hh[((size_t)gt * ND + d0) * ND + 2 * p + 1],
                            W_hh[((size_t)gt * ND + d0 + 1) * ND + 2 * p + 1]);
  }

  const float bp0 = bp[d0], bp1 = bp[d0 + 1];
  float bih[6], bhh[6];   // [gate*2 + dim]
#pragma unroll
  for (int gt = 0; gt < 3; ++gt)
#pragma unroll
    for (int d = 0; d < 2; ++d) {
      bih[gt * 2 + d] = b_ih[gt * ND + d0 + d];
      bhh[gt * 2 + d] = b_hh[gt * ND + d0 + d];
    }
  const float bi1h = bi1[h_b];
  const float bi2v = bi2[0];
  const float2 w2p = ((const float2*)Wi2)[lane];
  float2 lg2 = make_float2(0.f, 0.f), lb2 = lg2;
  if (tid < 512) {
    lg2 = ((const float2*)ln_g)[tid & 255];
    lb2 = ((const float2*)ln_b)[tid & 255];
  }
  __syncthreads();

  const int nL = nLevels[0];
  int epoch = 0;

  for (int L = 0; L < nL; ++L) {
    const int s = levelStart[L], e_ = levelStart[L + 1];
    for (int cs = s; cs < e_; cs += Wcap) {
      const int W = min(e_ - cs, Wcap);

      // ---- stage per-level metadata (immutable; parallel loads) ----
      if (tid < W) {
        const int g = levelList[cs + tid];
        sG[tid] = g;
        sTa[tid] = team_a[g];
        sTb[tid] = team_b[g];
        sAw[tid] = (float)a_won[g];
      }
      __syncthreads();

      // ===== R1: phase A (proj both rows -> ctx; gh + e_self -> stash) =====
      for (int w = wave * 4 + grpq; w < W; w += 64) {
        const int g = sG[w];
        const int ta = sTa[w], tb = sTb[w];
        const float aw = sAw[w];
        const float* rowA = emb + (size_t)ta * ND;
        const float* rowB = emb + (size_t)tb * ND;
        const float2 es0 = *(const float2*)(rowA + d0);
        const float2 es1 = *(const float2*)(rowB + d0);
        float acc[16];
#pragma unroll
        for (int i = 0; i < 16; ++i) acc[i] = 0.f;
#pragma unroll 8
        for (int j = 0; j < 16; ++j) {
          const int p = j * 16 + l4;
          const float2 va = *(const float2*)(rowA + 2 * p);
          const float2 vb = *(const float2*)(rowB + 2 * p);
          const float4 wS = wpS4[p];
          const float4 wO = wpO4[p];
          acc[0] += va.x * wS.x + va.y * wS.z + vb.x * wO.x + vb.y * wO.z;
          acc[1] += va.x * wS.y + va.y * wS.w + vb.x * wO.y + vb.y * wO.w;
          acc[2] += vb.x * wS.x + vb.y * wS.z + va.x * wO.x + va.y * wO.z;
          acc[3] += vb.x * wS.y + vb.y * wS.w + va.x * wO.y + va.y * wO.w;
#pragma unroll
          for (int gt = 0; gt < 3; ++gt) {
            const float4 q = whh4[gt * 256 + p];
            acc[4 + gt * 2 + 0]  += va.x * q.x + va.y * q.z;
            acc[4 + gt * 2 + 1]  += va.x * q.y + va.y * q.w;
            acc[10 + gt * 2 + 0] += vb.x * q.x + vb.y * q.z;
            acc[10 + gt * 2 + 1] += vb.x * q.y + vb.y * q.w;
          }
        }
#pragma unroll
        for (int j = 0; j < 2; ++j) {
          const int t = j * 16 + l4;
          if (t < NF + 1) {
            const float cv0 = (t < NF) ? fA[(size_t)g * NF + t] : aw;
            const float cv1 = (t < NF) ? fB[(size_t)g * NF + t] : 1.0f - aw;
            const float2 wt = wpT2[t];
            acc[0] += cv0 * wt.x; acc[1] += cv0 * wt.y;
            acc[2] += cv1 * wt.x; acc[3] += cv1 * wt.y;
          }
        }
#pragma unroll
        for (int off = 8; off > 0; off >>= 1) {
#pragma unroll
          for (int i = 0; i < 16; ++i) acc[i] += __shfl_xor(acc[i], off);
        }
        if (l4 == 0) {
          astore_f2(ctx + (size_t)g * 1024 + d0,
                    fmaxf(acc[0] + bp0, 0.f), fmaxf(acc[1] + bp1, 0.f));
          astore_f2(ctx + (size_t)g * 1024 + ND + d0,
                    fmaxf(acc[2] + bp0, 0.f), fmaxf(acc[3] + bp1, 0.f));
          sStash[w][0] = make_float4(acc[4], acc[5], acc[6], acc[7]);
          sStash[w][1] = make_float4(acc[8], acc[9], es0.x, es0.y);
          sStash[w][2] = make_float4(acc[10], acc[11], acc[12], acc[13]);
          sStash[w][3] = make_float4(acc[14], acc[15], es1.x, es1.y);
        }
      }
      grid_bar(goRep, arr, epoch);

      // ===== R2: phase C (gates -> nh, both rows) + B1 (hidden) =====
      for (int w = wave * 4 + grpq; w < W; w += 64) {
        const int g = sG[w];
        const float* p0 = ctx + (size_t)g * 1024;
        const float* p1 = p0 + ND;
        float acc[13];
#pragma unroll
        for (int i = 0; i < 13; ++i) acc[i] = 0.f;
#pragma unroll 8
        for (int j = 0; j < 16; ++j) {
          const int p = j * 16 + l4;
          const float2 x0 = *(const float2*)(p0 + 2 * p);
          const float2 x1 = *(const float2*)(p1 + 2 * p);
#pragma unroll
          for (int gt = 0; gt < 3; ++gt) {
            const float4 q = wih4[gt * 256 + p];
            acc[gt * 2 + 0]     += x0.x * q.x + x0.y * q.z;
            acc[gt * 2 + 1]     += x0.x * q.y + x0.y * q.w;
            acc[6 + gt * 2 + 0] += x1.x * q.x + x1.y * q.z;
            acc[6 + gt * 2 + 1] += x1.x * q.y + x1.y * q.w;
          }
          const float2 wi = wi12[p];
          const float2 xr = r_b ? x1 : x0;
          acc[12] += xr.x * wi.x + xr.y * wi.y;
        }
#pragma unroll
        for (int off = 8; off > 0; off >>= 1) {
#pragma unroll
          for (int i = 0; i < 13; ++i) acc[i] += __shfl_xor(acc[i], off);
        }
        if (l4 == 0) {
          const float4 s0 = sStash[w][0], s1 = sStash[w][1];
          const float4 s2 = sStash[w][2], s3 = sStash[w][3];
          {
            const float r0 = sigmf(acc[0] + bih[0] + s0.x + bhh[0]);
            const float r1 = sigmf(acc[1] + bih[1] + s0.y + bhh[1]);
            const float z0 = sigmf(acc[2] + bih[2] + s0.z + bhh[2]);
            const float z1 = sigmf(acc[3] + bih[3] + s0.w + bhh[3]);
            const float n0 = tanhf(acc[4] + bih[4] + r0 * (s1.x + bhh[4]));
            const float n1 = tanhf(acc[5] + bih[5] + r1 * (s1.y + bhh[5]));
            astore_f2(nhbuf + (size_t)w * 1024 + d0,
                      (1.f - z0) * n0 + z0 * s1.z,
                      (1.f - z1) * n1 + z1 * s1.w);
          }
          {
            const float r0 = sigmf(acc[6] + bih[0] + s2.x + bhh[0]);
            const float r1 = sigmf(acc[7] + bih[1] + s2.y + bhh[1]);
            const float z0 = sigmf(acc[8] + bih[2] + s2.z + bhh[2]);
            const float z1 = sigmf(acc[9] + bih[3] + s2.w + bhh[3]);
            const float n0 = tanhf(acc[10] + bih[4] + r0 * (s3.x + bhh[4]));
            const float n1 = tanhf(acc[11] + bih[5] + r1 * (s3.y + bhh[5]));
            astore_f2(nhbuf + (size_t)w * 1024 + ND + d0,
                      (1.f - z0) * n0 + z0 * s3.z,
                      (1.f - z1) * n1 + z1 * s3.w);
          }
          astore_f(hidbuf + (size_t)w * 256 + r_b * NH + h_b,
                   fmaxf(acc[12] + bi1h, 0.f));
        }
      }
      grid_bar(goRep, arr, epoch);

      // ===== R3: phase D (whole block per game): imp, blend, LN, write =====
      for (int w = b; w < W; w += NB) {
        const int ta = sTa[w], tb = sTb[w];
        if (wave < 2) {
          const float2 hv = *(const float2*)(hidbuf + (size_t)w * 256 + wave * NH + 2 * lane);
          float a = hv.x * w2p.x + hv.y * w2p.y;
#pragma unroll
          for (int off = 32; off > 0; off >>= 1) a += __shfl_xor(a, off);
          if (lane == 0) sImp[wave] = sigmf(a + bi2v);
        }
        __syncthreads();
        float ux = 0.f, uy = 0.f;
        if (tid < 512) {
          const int row = tid >> 8;
          const int e = 2 * (tid & 255);
          const int team = row ? tb : ta;
          const float imp = sImp[row];
          const float2 ev = *(const float2*)(emb + (size_t)team * ND + e);
          const float2 nv = *(const float2*)(nhbuf + (size_t)w * 1024 + (size_t)row * ND + e);
          ux = ev.x + imp * (nv.x - ev.x);
          uy = ev.y + imp * (nv.y - ev.y);
        }
        float sS = ux + uy, sQ = ux * ux + uy * uy;
#pragma unroll
        for (int off = 32; off > 0; off >>= 1) {
          sS += __shfl_xor(sS, off);
          sQ += __shfl_xor(sQ, off);
        }
        if (lane == 0) { sRed[0][wave] = sS; sRed[1][wave] = sQ; }
        __syncthreads();
        if (tid == 0) {
          const float S0 = sRed[0][0] + sRed[0][1] + sRed[0][2] + sRed[0][3];
          const float Q0 = sRed[1][0] + sRed[1][1] + sRed[1][2] + sRed[1][3];
          const float S1 = sRed[0][4] + sRed[0][5] + sRed[0][6] + sRed[0][7];
          const float Q1 = sRed[1][4] + sRed[1][5] + sRed[1][6] + sRed[1][7];
          const float mu0 = S0 * (1.0f / ND), mu1 = S1 * (1.0f / ND);
          const float v0 = Q0 * (1.0f / ND) - mu0 * mu0;
          const float v1 = Q1 * (1.0f / ND) - mu1 * mu1;
          sStat[0] = mu0; sStat[1] = 1.0f / sqrtf(v0 + 1e-5f);
          sStat[2] = mu1; sStat[3] = 1.0f / sqrtf(v1 + 1e-5f);
        }
        __syncthreads();
        if (tid < 512) {
          const int row = tid >> 8;
          const int e = 2 * (tid & 255);
          const float mu = sStat[row * 2], rs = sStat[row * 2 + 1];
          const float ox = (ux - mu) * rs * lg2.x + lb2.x;
          const float oy = (uy - mu) * rs * lg2.y + lb2.y;
          if (row == 0) {
            if (ta != tb) astore_f2(emb + (size_t)ta * ND + e, ox, oy);
          } else {
            astore_f2(emb + (size_t)tb * ND + e, ox, oy);
          }
        }
        __syncthreads();
      }
      grid_bar(goRep, arr, epoch);
    }
  }
}

extern "C" void kernel_launch(void* const* d_in, const int* in_sizes, int n_in,
                              void* d_out, int out_size, void* d_ws, size_t ws_size,
                              hipStream_t stream) {
  const float* emb_table = (const float*)d_in[0];
  const float* Wp    = (const float*)d_in[1];
  const float* bp    = (const float*)d_in[2];
  const float* W_ih  = (const float*)d_in[3];
  const float* b_ih  = (const float*)d_in[4];
  const float* W_hh  = (const float*)d_in[5];
  const float* b_hh  = (const float*)d_in[6];
  const float* ln_g  = (const float*)d_in[7];
  const float* ln_b  = (const float*)d_in[8];
  const float* Wi1   = (const float*)d_in[9];
  const float* bi1   = (const float*)d_in[10];
  const float* Wi2   = (const float*)d_in[11];
  const float* bi2   = (const float*)d_in[12];
  const float* fA    = (const float*)d_in[13];
  const float* fB    = (const float*)d_in[14];
  const int*   team_a = (const int*)d_in[15];
  const int*   team_b = (const int*)d_in[16];
  const int*   a_won  = (const int*)d_in[17];

  float* out = (float*)d_out;
  float* emb = out;
  float* ctx = out + (size_t)NT * ND;

  int* ip         = (int*)d_ws;
  int* goRep      = ip;                 // 32 lines
  int* arr        = ip + 32 * 32;       // NB lines
  int* nLevels    = arr + NB * 32;
  int* dep0       = nLevels + 32;
  int* dep1       = dep0 + NG;
  int* level      = dep1 + NG;
  int* hist       = level + NG;
  int* cursor     = hist + NG;
  int* levelStart = cursor + NG;        // NG+2
  int* levelList  = levelStart + NG + 2;
  const int flagInts = 32 * 32 + NB * 32;
  size_t control = (size_t)((char*)(levelList + NG) - (char*)d_ws);
  control = (control + 255) & ~(size_t)255;

  int Wcap = WCAP;
  {
    size_t avail = (ws_size > control + 4096)
        ? (ws_size - control) / ((size_t)(1024 + 256) * sizeof(float))
        : 8;
    if (avail < (size_t)Wcap) Wcap = (int)avail;
    if (Wcap < 8) Wcap = 8;
  }
  float* nhbuf  = (float*)((char*)d_ws + control);
  float* hidbuf = nhbuf + (size_t)Wcap * 1024;

  hipMemcpyAsync(emb, emb_table, (size_t)NT * ND * sizeof(float),
                 hipMemcpyDeviceToDevice, stream);
  zero_kernel<<<(flagInts + 255) / 256, 256, 0, stream>>>(ip, flagInts);
  deps_kernel<<<(NG + 255) / 256, 256, 0, stream>>>(team_a, team_b, dep0, dep1);
  levels_kernel<<<1, 1024, 0, stream>>>(dep0, dep1, level, nLevels);
  sort_kernel<<<1, 1024, 0, stream>>>(level, nLevels, hist, cursor, levelStart, levelList);
  game_kernel<<<NB, BLK, 0, stream>>>(
      Wp, bp, W_ih, b_ih, W_hh, b_hh, ln_g, ln_b, Wi1, bi1, Wi2, bi2,
      fA, fB, team_a, team_b, a_won, emb, ctx,
      levelStart, levelList, nLevels, nhbuf, hidbuf, goRep, arr, Wcap);
}